// Round 16
// baseline (468.260 us; speedup 1.0000x reference)
//
#include <hip/hip_runtime.h>

// BitDelta chained layers: per layer W = base + bd*mask (4096x4096 fp32),
// x = x @ W, x [16,4096].  Weight-streaming, memory-bound (134 MB/layer).
//
// R16 = R10 stream EXACTLY (grid 1024 = 64 kchunks x 16 cchunks, TPB=256,
// 4 waves, KW=16, float4 1 KB granule, depth-1 window prefetch, scalar-x,
// 12 KB tree reduce, wave-0 slab write) + FUSED stage-2 via decoupled
// last-block fold: after the slab write, tid0 does threadfence (release,
// wbl2) + device-scope atomicAdd on cnt[layer][cchunk]; the 64th arrival
// re-fences (acquire, inv -- cross-XCD safety), and its block folds the 64
// slabs for its 256-col range (fixed k order -> deterministic) into y.
// Dispatches per call: 1 counter memset + 4 layer kernels (was 9).

#define DD 4096
#define BB 16
#define KW 16                  // k-rows per wave
#define NW 4                   // waves per block
#define KC (KW * NW)           // 64 k-rows per block
#define VEC 4
#define CT 256                 // cols per block (64 lanes * 4)
#define TPB 256
#define KCHUNKS (DD / KC)      // 64
#define NCHUNKS (DD / CT)      // 16
#define OUT_ELEMS (BB * DD)    // 65536

typedef float f32x4 __attribute__((ext_vector_type(4)));

__global__ __launch_bounds__(TPB)
void bitdelta_layer(const float* __restrict__ x,
                    const float* __restrict__ base,
                    const float* __restrict__ mask,
                    const float* __restrict__ bitdelta,
                    int layer,
                    float* __restrict__ part,
                    unsigned int* __restrict__ cnt,
                    float* __restrict__ y) {
    __shared__ float red[16][3 * 64];   // 12 KB reduce buffer
    __shared__ int lastFlag;

    const int tid = threadIdx.x;
    const int l   = tid & 63;
    const int wid = __builtin_amdgcn_readfirstlane(tid >> 6);  // wave-uniform

    const int bid    = blockIdx.x;
    const int cchunk = bid & (NCHUNKS - 1);
    const int kchunk = bid >> 4;              // bid / NCHUNKS

    const int c0 = cchunk * CT + l * VEC;
    const int k0 = kchunk * KC + wid * KW;    // wave-uniform

    const float bd = bitdelta[layer];

    const float* wb = base + (size_t)k0 * DD + c0;
    const float* wm = mask + (size_t)k0 * DD + c0;
    const float* xp = x + k0;                 // wave-uniform base

    float acc[BB][VEC];
#pragma unroll
    for (int r = 0; r < BB; ++r)
#pragma unroll
        for (int c = 0; c < VEC; ++c) acc[r][c] = 0.0f;

    // ---- streaming k-loop: BYTE-IDENTICAL to R10 ----
    float4 b0 = *reinterpret_cast<const float4*>(wb);
    float4 b1 = *reinterpret_cast<const float4*>(wb + DD);
    float4 m0 = *reinterpret_cast<const float4*>(wm);
    float4 m1 = *reinterpret_cast<const float4*>(wm + DD);

#pragma unroll
    for (int kw = 0; kw < KW; kw += 2) {
        float4 nb0, nb1, nm0, nm1;
        if (kw + 2 < KW) {   // compile-time after full unroll
            const float* pb = wb + (size_t)(kw + 2) * DD;
            const float* pm = wm + (size_t)(kw + 2) * DD;
            nb0 = *reinterpret_cast<const float4*>(pb);
            nb1 = *reinterpret_cast<const float4*>(pb + DD);
            nm0 = *reinterpret_cast<const float4*>(pm);
            nm1 = *reinterpret_cast<const float4*>(pm + DD);
        }

        const float w00 = fmaf(bd, m0.x, b0.x);
        const float w01 = fmaf(bd, m0.y, b0.y);
        const float w02 = fmaf(bd, m0.z, b0.z);
        const float w03 = fmaf(bd, m0.w, b0.w);
        const float w10 = fmaf(bd, m1.x, b1.x);
        const float w11 = fmaf(bd, m1.y, b1.y);
        const float w12 = fmaf(bd, m1.z, b1.z);
        const float w13 = fmaf(bd, m1.w, b1.w);

#pragma unroll
        for (int r = 0; r < BB; ++r) {
            const float xv0 = xp[r * DD + kw];       // wave-uniform s_load
            const float xv1 = xp[r * DD + kw + 1];
            acc[r][0] = fmaf(xv0, w00, acc[r][0]);
            acc[r][1] = fmaf(xv0, w01, acc[r][1]);
            acc[r][2] = fmaf(xv0, w02, acc[r][2]);
            acc[r][3] = fmaf(xv0, w03, acc[r][3]);
            acc[r][0] = fmaf(xv1, w10, acc[r][0]);
            acc[r][1] = fmaf(xv1, w11, acc[r][1]);
            acc[r][2] = fmaf(xv1, w12, acc[r][2]);
            acc[r][3] = fmaf(xv1, w13, acc[r][3]);
        }

        if (kw + 2 < KW) { b0 = nb0; b1 = nb1; m0 = nm0; m1 = nm1; }
    }

    // 4-wave LDS reduce (R10 pattern).
#pragma unroll
    for (int t = 0; t < 4; ++t) {
        if (t) __syncthreads();
        if (wid != 0) {
#pragma unroll
            for (int e = 0; e < 16; ++e) {
                const int r = t * 4 + (e >> 2), c = e & 3;
                red[e][(wid - 1) * 64 + l] = acc[r][c];
            }
        }
        __syncthreads();
        if (wid == 0) {
#pragma unroll
            for (int e = 0; e < 16; ++e) {
                const int r = t * 4 + (e >> 2), c = e & 3;
                acc[r][c] += red[e][l] + red[e][64 + l] + red[e][128 + l];
            }
        }
    }

    // Wave 0 writes the block partial: [16][256] slab.
    if (wid == 0) {
        float* pp = part + (size_t)kchunk * OUT_ELEMS;
#pragma unroll
        for (int r = 0; r < BB; ++r) {
            f32x4 v = { acc[r][0], acc[r][1], acc[r][2], acc[r][3] };
            *reinterpret_cast<f32x4*>(&pp[r * DD + c0]) = v;
        }
    }

    // ---- decoupled last-block fold (fused stage 2) ----
    __syncthreads();   // compiler drains vmcnt before s_barrier -> stores done
    if (tid == 0) {
        __threadfence();                               // release (L2 writeback)
        const unsigned int old = __hip_atomic_fetch_add(
            &cnt[cchunk], 1u, __ATOMIC_ACQ_REL, __HIP_MEMORY_SCOPE_AGENT);
        if (old == KCHUNKS - 1) {
            __threadfence();                           // acquire (L2 invalidate)
            lastFlag = 1;
        } else {
            lastFlag = 0;
        }
    }
    __syncthreads();

    if (lastFlag) {
        // Fold 64 slabs x [16 rows x 256 cols] for this cchunk into y.
        // Thread t: float4-col ft = t&63, row group rg = t>>6 (rows rg+4g).
        const int ft    = tid & 63;
        const int rg    = tid >> 6;
        const int cbase = cchunk * CT + ft * 4;
        f32x4 s0 = 0.0f, s1 = 0.0f, s2 = 0.0f, s3 = 0.0f;
        for (int k = 0; k < KCHUNKS; ++k) {            // fixed order: deterministic
            const float* ps = part + (size_t)k * OUT_ELEMS + cbase;
            s0 += *reinterpret_cast<const f32x4*>(ps + (size_t)(rg     ) * DD);
            s1 += *reinterpret_cast<const f32x4*>(ps + (size_t)(rg +  4) * DD);
            s2 += *reinterpret_cast<const f32x4*>(ps + (size_t)(rg +  8) * DD);
            s3 += *reinterpret_cast<const f32x4*>(ps + (size_t)(rg + 12) * DD);
        }
        *reinterpret_cast<f32x4*>(y + (size_t)(rg     ) * DD + cbase) = s0;
        *reinterpret_cast<f32x4*>(y + (size_t)(rg +  4) * DD + cbase) = s1;
        *reinterpret_cast<f32x4*>(y + (size_t)(rg +  8) * DD + cbase) = s2;
        *reinterpret_cast<f32x4*>(y + (size_t)(rg + 12) * DD + cbase) = s3;
    }
}

extern "C" void kernel_launch(void* const* d_in, const int* in_sizes, int n_in,
                              void* d_out, int out_size, void* d_ws, size_t ws_size,
                              hipStream_t stream) {
    const float* x    = (const float*)d_in[0];   // [16,4096]
    const float* base = (const float*)d_in[1];   // [4,4096,4096]
    const float* mask = (const float*)d_in[2];   // [4,4096,4096]
    const float* bd   = (const float*)d_in[3];   // [4]
    float* out = (float*)d_out;                  // [16,4096] fp32

    float* part = (float*)d_ws;                  // 64 x 65536 floats = 16 MB
    float* y0   = part + (size_t)KCHUNKS * OUT_ELEMS;
    float* y1   = y0 + OUT_ELEMS;
    unsigned int* cnt = (unsigned int*)(y1 + OUT_ELEMS);   // 4 x 16 counters

    const size_t layer_stride = (size_t)DD * DD;
    const int    grid1 = KCHUNKS * NCHUNKS;      // 1024

    hipMemsetAsync(cnt, 0, 4 * NCHUNKS * sizeof(unsigned int), stream);

    bitdelta_layer<<<grid1, TPB, 0, stream>>>(x, base, mask, bd, 0, part,
                                              cnt + 0 * NCHUNKS, y0);
    bitdelta_layer<<<grid1, TPB, 0, stream>>>(y0, base + 1 * layer_stride,
                                              mask + 1 * layer_stride, bd, 1, part,
                                              cnt + 1 * NCHUNKS, y1);
    bitdelta_layer<<<grid1, TPB, 0, stream>>>(y1, base + 2 * layer_stride,
                                              mask + 2 * layer_stride, bd, 2, part,
                                              cnt + 2 * NCHUNKS, y0);
    bitdelta_layer<<<grid1, TPB, 0, stream>>>(y0, base + 3 * layer_stride,
                                              mask + 3 * layer_stride, bd, 3, part,
                                              cnt + 3 * NCHUNKS, out);
}

// Round 17
// 205.535 us; speedup vs baseline: 2.2783x; 2.2783x over previous
//
#include <hip/hip_runtime.h>

// BitDelta chained layers: per layer W = base + bd*mask (4096x4096 fp32),
// x = x @ W, x [16,4096].  Weight-streaming, memory-bound (134 MB/layer).
//
// R17 = R7's layer kernel EXACTLY (best stream shape at KCHUNKS=32:
// grid 512 = 32 kchunks x 16 cchunks, TPB=256 (4 waves), KW=32 k-rows per
// wave, float4 1 KB granule, depth-1 window prefetch, wave-uniform
// scalar-x, 12 KB 4-wave tree reduce, wave-0 slab write -> only 8 MB
// partial traffic) + R10's fast reduce shape (256 blocks x 64 threads,
// 1 wave/CU, lane owns one float4, 32 independent slab loads).
// Components measured in R7 (152.5 w/ slow reduce) and R10 (140.3 w/
// 64-slab partials); this pairs the cheaper halves of both.

#define DD 4096
#define BB 16
#define KW 32                  // k-rows per wave
#define NW 4                   // waves per block
#define KC (KW * NW)           // 128 k-rows per block
#define VEC 4
#define CT 256                 // cols per block (64 lanes * 4)
#define TPB 256
#define KCHUNKS (DD / KC)      // 32
#define NCHUNKS (DD / CT)      // 16
#define OUT_ELEMS (BB * DD)    // 65536

typedef float f32x4 __attribute__((ext_vector_type(4)));

__global__ __launch_bounds__(TPB)
void bitdelta_layer(const float* __restrict__ x,
                    const float* __restrict__ base,
                    const float* __restrict__ mask,
                    const float* __restrict__ bitdelta,
                    int layer,
                    float* __restrict__ part) {
    __shared__ float red[16][3 * 64];   // 12 KB reduce buffer

    const int tid = threadIdx.x;
    const int l   = tid & 63;
    const int wid = __builtin_amdgcn_readfirstlane(tid >> 6);  // wave-uniform

    const int bid    = blockIdx.x;
    const int cchunk = bid & (NCHUNKS - 1);
    const int kchunk = bid >> 4;              // bid / NCHUNKS

    const int c0 = cchunk * CT + l * VEC;
    const int k0 = kchunk * KC + wid * KW;    // wave-uniform

    const float bd = bitdelta[layer];

    const float* wb = base + (size_t)k0 * DD + c0;
    const float* wm = mask + (size_t)k0 * DD + c0;
    const float* xp = x + k0;                 // wave-uniform base

    float acc[BB][VEC];
#pragma unroll
    for (int r = 0; r < BB; ++r)
#pragma unroll
        for (int c = 0; c < VEC; ++c) acc[r][c] = 0.0f;

    // Window 0 (2 k-rows): float4 loads = 1 KB/wave-instruction.
    float4 b0 = *reinterpret_cast<const float4*>(wb);
    float4 b1 = *reinterpret_cast<const float4*>(wb + DD);
    float4 m0 = *reinterpret_cast<const float4*>(wm);
    float4 m1 = *reinterpret_cast<const float4*>(wm + DD);

#pragma unroll
    for (int kw = 0; kw < KW; kw += 2) {
        float4 nb0, nb1, nm0, nm1;
        if (kw + 2 < KW) {   // compile-time after full unroll
            const float* pb = wb + (size_t)(kw + 2) * DD;
            const float* pm = wm + (size_t)(kw + 2) * DD;
            nb0 = *reinterpret_cast<const float4*>(pb);
            nb1 = *reinterpret_cast<const float4*>(pb + DD);
            nm0 = *reinterpret_cast<const float4*>(pm);
            nm1 = *reinterpret_cast<const float4*>(pm + DD);
        }

        const float w00 = fmaf(bd, m0.x, b0.x);
        const float w01 = fmaf(bd, m0.y, b0.y);
        const float w02 = fmaf(bd, m0.z, b0.z);
        const float w03 = fmaf(bd, m0.w, b0.w);
        const float w10 = fmaf(bd, m1.x, b1.x);
        const float w11 = fmaf(bd, m1.y, b1.y);
        const float w12 = fmaf(bd, m1.z, b1.z);
        const float w13 = fmaf(bd, m1.w, b1.w);

#pragma unroll
        for (int r = 0; r < BB; ++r) {
            // Wave-uniform -> scalar loads on the SMEM pipe.
            const float xv0 = xp[r * DD + kw];
            const float xv1 = xp[r * DD + kw + 1];
            acc[r][0] = fmaf(xv0, w00, acc[r][0]);
            acc[r][1] = fmaf(xv0, w01, acc[r][1]);
            acc[r][2] = fmaf(xv0, w02, acc[r][2]);
            acc[r][3] = fmaf(xv0, w03, acc[r][3]);
            acc[r][0] = fmaf(xv1, w10, acc[r][0]);
            acc[r][1] = fmaf(xv1, w11, acc[r][1]);
            acc[r][2] = fmaf(xv1, w12, acc[r][2]);
            acc[r][3] = fmaf(xv1, w13, acc[r][3]);
        }

        if (kw + 2 < KW) { b0 = nb0; b1 = nb1; m0 = nm0; m1 = nm1; }
    }

    // 4-wave LDS reduce, four rounds of 16 elements (12 KB, conflict-free).
#pragma unroll
    for (int t = 0; t < 4; ++t) {
        if (t) __syncthreads();
        if (wid != 0) {
#pragma unroll
            for (int e = 0; e < 16; ++e) {
                const int r = t * 4 + (e >> 2), c = e & 3;
                red[e][(wid - 1) * 64 + l] = acc[r][c];
            }
        }
        __syncthreads();
        if (wid == 0) {
#pragma unroll
            for (int e = 0; e < 16; ++e) {
                const int r = t * 4 + (e >> 2), c = e & 3;
                acc[r][c] += red[e][l] + red[e][64 + l] + red[e][128 + l];
            }
        }
    }

    // Wave 0 writes the block partial: [16][256] slab, float4 stores.
    if (wid == 0) {
        float* pp = part + (size_t)kchunk * OUT_ELEMS;
#pragma unroll
        for (int r = 0; r < BB; ++r) {
            const float4 v = make_float4(acc[r][0], acc[r][1], acc[r][2], acc[r][3]);
            *reinterpret_cast<float4*>(&pp[r * DD + c0]) = v;
        }
    }
}

// Stage 2: out[e] = sum_k part[k][e].  256 blocks x 64 threads: one wave
// per CU; lane owns one float4 (1 KB contiguous per slab-load); 32
// independent slab loads per thread (deep ILP).
__global__ __launch_bounds__(64)
void reduce_partials(const float* __restrict__ part, float* __restrict__ out) {
    const int idx = (blockIdx.x * 64 + threadIdx.x) * 4;   // float4 base
    f32x4 a = *reinterpret_cast<const f32x4*>(&part[idx]);
#pragma unroll
    for (int k = 1; k < KCHUNKS; ++k) {
        const f32x4 p = *reinterpret_cast<const f32x4*>(
            &part[(size_t)k * OUT_ELEMS + idx]);
        a += p;
    }
    *reinterpret_cast<f32x4*>(&out[idx]) = a;
}

extern "C" void kernel_launch(void* const* d_in, const int* in_sizes, int n_in,
                              void* d_out, int out_size, void* d_ws, size_t ws_size,
                              hipStream_t stream) {
    const float* x    = (const float*)d_in[0];   // [16,4096]
    const float* base = (const float*)d_in[1];   // [4,4096,4096]
    const float* mask = (const float*)d_in[2];   // [4,4096,4096]
    const float* bd   = (const float*)d_in[3];   // [4]
    float* out = (float*)d_out;                  // [16,4096] fp32

    float* part = (float*)d_ws;                  // 32 x 65536 floats = 8 MB
    float* y0   = part + (size_t)KCHUNKS * OUT_ELEMS;
    float* y1   = y0 + OUT_ELEMS;

    const size_t layer_stride = (size_t)DD * DD;
    const int    grid1 = KCHUNKS * NCHUNKS;      // 512
    const int    grid2 = OUT_ELEMS / (64 * 4);   // 256 blocks x 64 threads

    bitdelta_layer<<<grid1, TPB, 0, stream>>>(x, base, mask, bd, 0, part);
    reduce_partials<<<grid2, 64, 0, stream>>>(part, y0);

    bitdelta_layer<<<grid1, TPB, 0, stream>>>(y0, base + 1 * layer_stride,
                                              mask + 1 * layer_stride, bd, 1, part);
    reduce_partials<<<grid2, 64, 0, stream>>>(part, y1);

    bitdelta_layer<<<grid1, TPB, 0, stream>>>(y1, base + 2 * layer_stride,
                                              mask + 2 * layer_stride, bd, 2, part);
    reduce_partials<<<grid2, 64, 0, stream>>>(part, y0);

    bitdelta_layer<<<grid1, TPB, 0, stream>>>(y0, base + 3 * layer_stride,
                                              mask + 3 * layer_stride, bd, 3, part);
    reduce_partials<<<grid2, 64, 0, stream>>>(part, out);
}

// Round 18
// 198.313 us; speedup vs baseline: 2.3612x; 1.0364x over previous
//
#include <hip/hip_runtime.h>

// BitDelta chained layers: per layer W = base + bd*mask (4096x4096 fp32),
// x = x @ W, x [16,4096].  Weight-streaming, memory-bound (134 MB/layer).
//
// R18: SINGLE-STREAM blocks via distributivity: out = x*B + bd*(x*M).
// Grid 1024 = 512 base-blocks + 512 mask-blocks; each block streams ONE
// contiguous array region (tests stream-mixing as the 4.7 TB/s culprit;
// every prior variant interleaved base+mask per wave).  TPB=256 (4 waves),
// 4 blocks/CU -> 16 waves/CU (R10 operating point).  Wave owns KW=32
// k-rows of one stream; 4-row window, depth-1 prefetch -> 4 float4 in
// flight/wave (= R10).  No weight-prep FMAs in the loop; bd folded into
// the mask-blocks' slab write.  12 KB tree reduce as R10.  Partials:
// 32 base + 32 mask slabs = 16 MB; stage-2 reduce BYTE-IDENTICAL to R10
// (sums 64 slabs).

#define DD 4096
#define BB 16
#define KW 32                  // k-rows per wave (one stream)
#define NW 4                   // waves per block
#define KC (KW * NW)           // 128 k-rows per block
#define VEC 4
#define CT 256                 // cols per block (64 lanes * 4)
#define TPB 256
#define KCHUNKS (DD / KC)      // 32 per stream
#define KTOT (2 * KCHUNKS)     // 64 slabs total
#define NCHUNKS (DD / CT)      // 16
#define OUT_ELEMS (BB * DD)    // 65536

typedef float f32x4 __attribute__((ext_vector_type(4)));

__global__ __launch_bounds__(TPB)
void bitdelta_layer(const float* __restrict__ x,
                    const float* __restrict__ base,
                    const float* __restrict__ mask,
                    const float* __restrict__ bitdelta,
                    int layer,
                    float* __restrict__ part) {
    __shared__ float red[16][3 * 64];   // 12 KB reduce buffer

    const int tid = threadIdx.x;
    const int l   = tid & 63;
    const int wid = __builtin_amdgcn_readfirstlane(tid >> 6);  // wave-uniform

    const int bid    = blockIdx.x;
    const int isMask = bid >> 9;              // 0: base-GEMM, 1: mask-GEMM
    const int sbid   = bid & 511;
    const int cchunk = sbid & (NCHUNKS - 1);
    const int kchunk = sbid >> 4;             // 0..31

    const int c0 = cchunk * CT + l * VEC;
    const int k0 = kchunk * KC + wid * KW;    // wave-uniform

    const float bd    = bitdelta[layer];
    const float scale = isMask ? bd : 1.0f;

    const float* src = isMask ? mask : base;
    const float* ws  = src + (size_t)k0 * DD + c0;   // single stream
    const float* xp  = x + k0;                        // wave-uniform base

    float acc[BB][VEC];
#pragma unroll
    for (int r = 0; r < BB; ++r)
#pragma unroll
        for (int c = 0; c < VEC; ++c) acc[r][c] = 0.0f;

    // Window 0: 4 k-rows of ONE stream (4 float4 = 4 loads in flight).
    float4 w0 = *reinterpret_cast<const float4*>(ws);
    float4 w1 = *reinterpret_cast<const float4*>(ws + DD);
    float4 w2 = *reinterpret_cast<const float4*>(ws + 2 * (size_t)DD);
    float4 w3 = *reinterpret_cast<const float4*>(ws + 3 * (size_t)DD);

#pragma unroll
    for (int kw = 0; kw < KW; kw += 4) {
        float4 n0, n1, n2, n3;
        if (kw + 4 < KW) {   // compile-time after full unroll
            const float* pn = ws + (size_t)(kw + 4) * DD;
            n0 = *reinterpret_cast<const float4*>(pn);
            n1 = *reinterpret_cast<const float4*>(pn + DD);
            n2 = *reinterpret_cast<const float4*>(pn + 2 * (size_t)DD);
            n3 = *reinterpret_cast<const float4*>(pn + 3 * (size_t)DD);
        }

#pragma unroll
        for (int r = 0; r < BB; ++r) {
            // Wave-uniform -> scalar loads on the SMEM pipe.
            const float xv0 = xp[r * DD + kw];
            const float xv1 = xp[r * DD + kw + 1];
            const float xv2 = xp[r * DD + kw + 2];
            const float xv3 = xp[r * DD + kw + 3];
            acc[r][0] = fmaf(xv0, w0.x, acc[r][0]);
            acc[r][1] = fmaf(xv0, w0.y, acc[r][1]);
            acc[r][2] = fmaf(xv0, w0.z, acc[r][2]);
            acc[r][3] = fmaf(xv0, w0.w, acc[r][3]);
            acc[r][0] = fmaf(xv1, w1.x, acc[r][0]);
            acc[r][1] = fmaf(xv1, w1.y, acc[r][1]);
            acc[r][2] = fmaf(xv1, w1.z, acc[r][2]);
            acc[r][3] = fmaf(xv1, w1.w, acc[r][3]);
            acc[r][0] = fmaf(xv2, w2.x, acc[r][0]);
            acc[r][1] = fmaf(xv2, w2.y, acc[r][1]);
            acc[r][2] = fmaf(xv2, w2.z, acc[r][2]);
            acc[r][3] = fmaf(xv2, w2.w, acc[r][3]);
            acc[r][0] = fmaf(xv3, w3.x, acc[r][0]);
            acc[r][1] = fmaf(xv3, w3.y, acc[r][1]);
            acc[r][2] = fmaf(xv3, w3.z, acc[r][2]);
            acc[r][3] = fmaf(xv3, w3.w, acc[r][3]);
        }

        if (kw + 4 < KW) { w0 = n0; w1 = n1; w2 = n2; w3 = n3; }
    }

    // 4-wave LDS reduce, four rounds of 16 elements (12 KB, conflict-free).
#pragma unroll
    for (int t = 0; t < 4; ++t) {
        if (t) __syncthreads();
        if (wid != 0) {
#pragma unroll
            for (int e = 0; e < 16; ++e) {
                const int r = t * 4 + (e >> 2), c = e & 3;
                red[e][(wid - 1) * 64 + l] = acc[r][c];
            }
        }
        __syncthreads();
        if (wid == 0) {
#pragma unroll
            for (int e = 0; e < 16; ++e) {
                const int r = t * 4 + (e >> 2), c = e & 3;
                acc[r][c] += red[e][l] + red[e][64 + l] + red[e][128 + l];
            }
        }
    }

    // Wave 0 writes the scaled block partial (slab kchunk, or 32+kchunk
    // for mask blocks; scale folds bd into the mask partial).
    if (wid == 0) {
        float* pp = part + (size_t)(isMask * KCHUNKS + kchunk) * OUT_ELEMS;
#pragma unroll
        for (int r = 0; r < BB; ++r) {
            f32x4 v = { acc[r][0] * scale, acc[r][1] * scale,
                        acc[r][2] * scale, acc[r][3] * scale };
            *reinterpret_cast<f32x4*>(&pp[r * DD + c0]) = v;
        }
    }
}

// Stage 2: out[e] = sum over 64 slabs (32 base + 32 scaled-mask).
// 256 blocks x 64 threads (R10-proven shape).
__global__ __launch_bounds__(64)
void reduce_partials(const float* __restrict__ part, float* __restrict__ out) {
    const int idx = (blockIdx.x * 64 + threadIdx.x) * 4;   // float4 base
    f32x4 a = *reinterpret_cast<const f32x4*>(&part[idx]);
#pragma unroll
    for (int k = 1; k < KTOT; ++k) {
        const f32x4 p = *reinterpret_cast<const f32x4*>(
            &part[(size_t)k * OUT_ELEMS + idx]);
        a += p;
    }
    *reinterpret_cast<f32x4*>(&out[idx]) = a;
}

extern "C" void kernel_launch(void* const* d_in, const int* in_sizes, int n_in,
                              void* d_out, int out_size, void* d_ws, size_t ws_size,
                              hipStream_t stream) {
    const float* x    = (const float*)d_in[0];   // [16,4096]
    const float* base = (const float*)d_in[1];   // [4,4096,4096]
    const float* mask = (const float*)d_in[2];   // [4,4096,4096]
    const float* bd   = (const float*)d_in[3];   // [4]
    float* out = (float*)d_out;                  // [16,4096] fp32

    float* part = (float*)d_ws;                  // 64 x 65536 floats = 16 MB
    float* y0   = part + (size_t)KTOT * OUT_ELEMS;
    float* y1   = y0 + OUT_ELEMS;

    const size_t layer_stride = (size_t)DD * DD;
    const int    grid1 = 2 * KCHUNKS * NCHUNKS;  // 1024 (512 base + 512 mask)
    const int    grid2 = OUT_ELEMS / (64 * 4);   // 256 blocks x 64 threads

    bitdelta_layer<<<grid1, TPB, 0, stream>>>(x, base, mask, bd, 0, part);
    reduce_partials<<<grid2, 64, 0, stream>>>(part, y0);

    bitdelta_layer<<<grid1, TPB, 0, stream>>>(y0, base + 1 * layer_stride,
                                              mask + 1 * layer_stride, bd, 1, part);
    reduce_partials<<<grid2, 64, 0, stream>>>(part, y1);

    bitdelta_layer<<<grid1, TPB, 0, stream>>>(y1, base + 2 * layer_stride,
                                              mask + 2 * layer_stride, bd, 2, part);
    reduce_partials<<<grid2, 64, 0, stream>>>(part, y0);

    bitdelta_layer<<<grid1, TPB, 0, stream>>>(y0, base + 3 * layer_stride,
                                              mask + 3 * layer_stride, bd, 3, part);
    reduce_partials<<<grid2, 64, 0, stream>>>(part, out);
}